// Round 4
// baseline (969.010 us; speedup 1.0000x reference)
//
#include <hip/hip_runtime.h>
#include <stdint.h>

#define NN 50000
#define EE 800000
#define GG 128
#define DF 128
#define DE 256
#define NCHUNK ((NN + 255) / 256)   // 196
#define LSTR 36                      // LDS row stride (u16) — 72B rotates banks, gcd(18,32)=2

typedef unsigned short u16;
typedef __bf16 bf16x8 __attribute__((ext_vector_type(8)));
typedef float f32x4 __attribute__((ext_vector_type(4)));

__device__ __forceinline__ float bf2f(u16 u) {
  union { unsigned int i; float f; } x; x.i = ((unsigned int)u) << 16; return x.f;
}
__device__ __forceinline__ u16 f2bf(float f) {
  union { float f; unsigned int i; } x; x.f = f;
  unsigned int i = x.i;
  return (u16)((i + 0x7fffu + ((i >> 16) & 1u)) >> 16);
}

// ---------------- dtype detection ----------------
__global__ void detect_kernel(const u16* __restrict__ xr,
                              const unsigned* __restrict__ ei_words,
                              int* __restrict__ flags) {
  int i = blockIdx.x * 256 + threadIdx.x;
  int found = 0;
  u16 a = xr[i * 2], b = xr[i * 2 + 1];
  if (((a >> 7) & 0xFFu) == 0xFFu) found = 1;
  if (((b >> 7) & 0xFFu) == 0xFFu) found = 1;
  if (__ballot(found)) {
    if ((threadIdx.x & 63) == 0) atomicOr(&flags[0], 1);
  }
  if (blockIdx.x == 0 && threadIdx.x < 64) {
    unsigned w = ei_words[threadIdx.x * 2 + 1];
    if (__ballot(w != 0u)) {
      if (threadIdx.x == 0) atomicOr(&flags[1], 1);
    }
  }
}

// ---------------- input normalization ----------------
struct ConvSeg { const void* src; u16* dst; int start_blk; int n; };
struct ConvArgs { ConvSeg s[13]; int nseg; };

__global__ void conv_many(ConvArgs A, const int* __restrict__ flags) {
  int f32f = flags[0];
  int b = blockIdx.x;
  for (int i = 0; i < A.nseg; i++) {
    int nb = (A.s[i].n + 255) >> 8;
    if (b >= A.s[i].start_blk && b < A.s[i].start_blk + nb) {
      int idx = ((b - A.s[i].start_blk) << 8) + threadIdx.x;
      if (idx < A.s[i].n) {
        u16 v = f32f ? f2bf(((const float*)A.s[i].src)[idx])
                     : ((const u16*)A.s[i].src)[idx];
        A.s[i].dst[idx] = v;
      }
      return;
    }
  }
}

__global__ void conv_idx(const void* __restrict__ ei, const void* __restrict__ batch,
                         int* __restrict__ src32, int* __restrict__ dst32,
                         int* __restrict__ batch32, const int* __restrict__ flags) {
  int i64 = (flags[1] == 0);
  int i = blockIdx.x * blockDim.x + threadIdx.x;
  if (i < EE) {
    int s, d;
    if (i64) {
      s = (int)((const long long*)ei)[i];
      d = (int)((const long long*)ei)[EE + i];
    } else {
      s = ((const int*)ei)[i];
      d = ((const int*)ei)[EE + i];
    }
    src32[i] = min(max(s, 0), NN - 1);
    dst32[i] = min(max(d, 0), NN - 1);
  }
  if (i < NN) {
    int bv = i64 ? (int)((const long long*)batch)[i] : ((const int*)batch)[i];
    batch32[i] = min(max(bv, 0), GG - 1);
  }
}

// ---------------- CSR build ----------------
__global__ void hist_kernel(const int* __restrict__ dst, int* __restrict__ counts, int E) {
  int e = blockIdx.x * blockDim.x + threadIdx.x;
  if (e < E) atomicAdd(&counts[dst[e]], 1);
}

__global__ void chunk_sum_kernel(const int* __restrict__ counts, int* __restrict__ partial, int n) {
  __shared__ int sh[256];
  int i = blockIdx.x * 256 + threadIdx.x;
  sh[threadIdx.x] = (i < n) ? counts[i] : 0;
  __syncthreads();
  for (int off = 128; off > 0; off >>= 1) {
    if (threadIdx.x < off) sh[threadIdx.x] += sh[threadIdx.x + off];
    __syncthreads();
  }
  if (threadIdx.x == 0) partial[blockIdx.x] = sh[0];
}

__global__ void scan_partial_kernel(int* __restrict__ partial, int np) {
  __shared__ int sh[256];
  int tid = threadIdx.x;
  int x = (tid < np) ? partial[tid] : 0;
  sh[tid] = x;
  __syncthreads();
  for (int off = 1; off < 256; off <<= 1) {
    int v = (tid >= off) ? sh[tid - off] : 0;
    __syncthreads();
    sh[tid] += v;
    __syncthreads();
  }
  if (tid < np) partial[tid] = sh[tid] - x;
}

__global__ void write_rowptr_kernel(int* __restrict__ counts, const int* __restrict__ partial,
                                    int* __restrict__ row_ptr, int n) {
  __shared__ int sh[256];
  int tid = threadIdx.x;
  int i = blockIdx.x * 256 + tid;
  int x = (i < n) ? counts[i] : 0;
  sh[tid] = x;
  __syncthreads();
  for (int off = 1; off < 256; off <<= 1) {
    int v = (tid >= off) ? sh[tid - off] : 0;
    __syncthreads();
    sh[tid] += v;
    __syncthreads();
  }
  int base = partial[blockIdx.x];
  if (i < n) {
    row_ptr[i + 1] = base + sh[tid];
    counts[i] = base + sh[tid] - x;
  }
  if (i == 0) row_ptr[0] = 0;
}

__global__ void scatter_kernel(const int* __restrict__ srcA, const int* __restrict__ dstA,
                               int* __restrict__ cursor, int* __restrict__ col_src, int E) {
  int e = blockIdx.x * blockDim.x + threadIdx.x;
  if (e < E) {
    int slot = atomicAdd(&cursor[dstA[e]], 1);
    col_src[slot] = srcA[e];
  }
}

__global__ void graph_start_kernel(const int* __restrict__ batch, int* __restrict__ gs, int n) {
  int g = threadIdx.x;
  if (g > GG) return;
  int lo = 0, hi = n;
  while (lo < hi) { int mid = (lo + hi) >> 1; if (batch[mid] < g) lo = mid + 1; else hi = mid; }
  gs[g] = lo;
}

// ---------------- weight prep ----------------
__device__ __forceinline__ u16 ldw(const void* p, int idx, int f) {
  return f ? f2bf(((const float*)p)[idx]) : ((const u16*)p)[idx];
}

struct WPtrs {
  const void* Wl[4]; const void* Wr[4]; const void* Wm[4]; const void* fc1W;
  u16* WcatT[4]; u16* WmT[4]; u16* fc1WT;
};

__global__ void prep_w_kernel(WPtrs P, const int* __restrict__ flags) {
  int f = flags[0];
  if (blockIdx.x >= 4096) {
    // fc1W^T: [256][1024] from fc1W [1024][256]
    int idx = ((blockIdx.x - 4096) << 8) + threadIdx.x;   // 1024 blocks * 256 = 262144
    int n = idx >> 10, k = idx & 1023;
    P.fc1WT[idx] = ldw(P.fc1W, k * 256 + n, f);
    return;
  }
  int seg = blockIdx.x >> 9;
  int idx = ((blockIdx.x & 511) << 8) + threadIdx.x;
  if (seg < 4) {
    int l = seg;
    int din = (l == 0) ? DF : DE;
    int K = 2 * din;
    if (idx < 256 * K) {
      int n = idx / K, k = idx - n * K;
      u16 v = (k < din) ? ldw(P.Wl[l], k * 256 + n, f) : ldw(P.Wr[l], (k - din) * 256 + n, f);
      P.WcatT[l][idx] = v;
    }
  } else {
    int l = seg - 4;
    if (idx < 256 * 256) {
      int n = idx >> 8, k = idx & 255;
      P.WmT[l][idx] = ldw(P.Wm[l], k * 256 + n, f);
    }
  }
}

// ---------------- per-node max aggregation (one wave per node) ----------------
template <int VPL>
__global__ __launch_bounds__(256) void segmax_kernel(
    const u16* __restrict__ feat, int fstride,
    const int* __restrict__ row_ptr, const int* __restrict__ col_src,
    u16* __restrict__ agg_out, int ostride,
    u16* __restrict__ copy_dst, int n) {
  int wave = blockIdx.x * 4 + (threadIdx.x >> 6);
  if (wave >= n) return;
  int lane = threadIdx.x & 63;
  int beg = row_ptr[wave], end = row_ptr[wave + 1];
  float m[VPL];
#pragma unroll
  for (int j = 0; j < VPL; j++) m[j] = -INFINITY;
  const u16* fb = feat + lane * VPL;
  int e = beg;
  for (; e + 2 <= end; e += 2) {
    int s0 = col_src[e], s1 = col_src[e + 1];
    const u16* p0 = fb + (long)s0 * fstride;
    const u16* p1 = fb + (long)s1 * fstride;
    if (VPL == 4) {
      ushort4 a = *(const ushort4*)p0;
      ushort4 b = *(const ushort4*)p1;
      m[0] = fmaxf(m[0], fmaxf(bf2f(a.x), bf2f(b.x)));
      m[1] = fmaxf(m[1], fmaxf(bf2f(a.y), bf2f(b.y)));
      m[2] = fmaxf(m[2], fmaxf(bf2f(a.z), bf2f(b.z)));
      m[3] = fmaxf(m[3], fmaxf(bf2f(a.w), bf2f(b.w)));
    } else {
      ushort2 a = *(const ushort2*)p0;
      ushort2 b = *(const ushort2*)p1;
      m[0] = fmaxf(m[0], fmaxf(bf2f(a.x), bf2f(b.x)));
      m[1] = fmaxf(m[1], fmaxf(bf2f(a.y), bf2f(b.y)));
    }
  }
  if (e < end) {
    int s0 = col_src[e];
    const u16* p0 = fb + (long)s0 * fstride;
    if (VPL == 4) {
      ushort4 a = *(const ushort4*)p0;
      m[0] = fmaxf(m[0], bf2f(a.x)); m[1] = fmaxf(m[1], bf2f(a.y));
      m[2] = fmaxf(m[2], bf2f(a.z)); m[3] = fmaxf(m[3], bf2f(a.w));
    } else {
      ushort2 a = *(const ushort2*)p0;
      m[0] = fmaxf(m[0], bf2f(a.x)); m[1] = fmaxf(m[1], bf2f(a.y));
    }
  }
  if (beg == end) {
#pragma unroll
    for (int j = 0; j < VPL; j++) m[j] = 0.f;
  }
  u16* op = agg_out + (long)wave * ostride + lane * VPL;
  if (VPL == 4) {
    ushort4 o; o.x = f2bf(m[0]); o.y = f2bf(m[1]); o.z = f2bf(m[2]); o.w = f2bf(m[3]);
    *(ushort4*)op = o;
  } else {
    ushort2 o; o.x = f2bf(m[0]); o.y = f2bf(m[1]);
    *(ushort2*)op = o;
  }
  if (copy_dst) {
    const u16* xp = feat + (long)wave * fstride + lane * VPL;
    u16* cp = copy_dst + (long)wave * ostride + lane * VPL;
    if (VPL == 4) *(ushort4*)cp = *(const ushort4*)xp;
    else          *(ushort2*)cp = *(const ushort2*)xp;
  }
}

// ---------------- MFMA GEMM: C[M,256] = op(A[M,K] @ B[K,256] + bias) ----------------
// 128x256 tile, 4 waves in 2x2 layout (64 rows x 128 cols each), acc[4][8]
__global__ __launch_bounds__(256) void gemm256(
    const u16* __restrict__ A, int lda, int K,
    const u16* __restrict__ BT,       // [256][K]
    const u16* __restrict__ bias,
    u16* __restrict__ C, int ldc,
    int M, int relu_flag) {
  __shared__ u16 lsA[128 * LSTR];
  __shared__ u16 lsB[256 * LSTR];
  int tid = threadIdx.x;
  int lane = tid & 63, w = tid >> 6;
  int bm = blockIdx.x;
  int wm = (w & 1) << 6, wn = (w >> 1) << 7;
  int ln15 = lane & 15, quad = lane >> 4;

  f32x4 acc[4][8] = {};

  int r0 = tid >> 2;            // 0..63
  int kc = (tid & 3) << 3;      // 0,8,16,24
  long a0 = (long)min(bm * 128 + r0, M - 1) * lda + kc;
  long a1 = (long)min(bm * 128 + r0 + 64, M - 1) * lda + kc;
  const u16* gB0 = BT + (long)r0 * K + kc;
  const u16* gB1 = BT + (long)(r0 + 64) * K + kc;
  const u16* gB2 = BT + (long)(r0 + 128) * K + kc;
  const u16* gB3 = BT + (long)(r0 + 192) * K + kc;
  u16* sA0 = lsA + r0 * LSTR + kc;  u16* sA1 = sA0 + 64 * LSTR;
  u16* sB0 = lsB + r0 * LSTR + kc;
  u16* sB1 = sB0 + 64 * LSTR;
  u16* sB2 = sB0 + 128 * LSTR;
  u16* sB3 = sB0 + 192 * LSTR;

  for (int k0 = 0; k0 < K; k0 += 32) {
    bf16x8 va0 = *(const bf16x8*)(A + a0 + k0);
    bf16x8 va1 = *(const bf16x8*)(A + a1 + k0);
    bf16x8 vb0 = *(const bf16x8*)(gB0 + k0);
    bf16x8 vb1 = *(const bf16x8*)(gB1 + k0);
    bf16x8 vb2 = *(const bf16x8*)(gB2 + k0);
    bf16x8 vb3 = *(const bf16x8*)(gB3 + k0);
    __syncthreads();
    *(bf16x8*)sA0 = va0; *(bf16x8*)sA1 = va1;
    *(bf16x8*)sB0 = vb0; *(bf16x8*)sB1 = vb1;
    *(bf16x8*)sB2 = vb2; *(bf16x8*)sB3 = vb3;
    __syncthreads();
    bf16x8 af[4], bf[8];
#pragma unroll
    for (int t = 0; t < 4; t++)
      af[t] = *(const bf16x8*)(lsA + (wm + t * 16 + ln15) * LSTR + quad * 8);
#pragma unroll
    for (int t = 0; t < 8; t++)
      bf[t] = *(const bf16x8*)(lsB + (wn + t * 16 + ln15) * LSTR + quad * 8);
#pragma unroll
    for (int mt = 0; mt < 4; mt++)
#pragma unroll
      for (int nt = 0; nt < 8; nt++)
        acc[mt][nt] = __builtin_amdgcn_mfma_f32_16x16x32_bf16(af[mt], bf[nt], acc[mt][nt], 0, 0, 0);
  }

  float bv[8];
#pragma unroll
  for (int nt = 0; nt < 8; nt++)
    bv[nt] = bf2f(bias[wn + nt * 16 + ln15]);

#pragma unroll
  for (int mt = 0; mt < 4; mt++) {
    int row0 = bm * 128 + wm + mt * 16 + quad * 4;
#pragma unroll
    for (int r = 0; r < 4; r++) {
      int row = row0 + r;
      if (row < M) {
#pragma unroll
        for (int nt = 0; nt < 8; nt++) {
          float v = acc[mt][nt][r] + bv[nt];
          if (relu_flag) v = fmaxf(v, 0.f);
          C[(long)row * ldc + wn + nt * 16 + ln15] = f2bf(v);
        }
      }
    }
  }
}

// ---------------- per-layer global max pool -> bf16 gpool[:, l*256:] ----------------
__global__ void pool_kernel(const u16* __restrict__ h, const int* __restrict__ gs,
                            u16* __restrict__ g_pool, int l) {
  int g = blockIdx.x;
  int c = threadIdx.x & 255, ty = threadIdx.x >> 8;
  int beg = gs[g], end = gs[g + 1];
  float m = -INFINITY;
  for (int n = beg + ty; n < end; n += 4)
    m = fmaxf(m, bf2f(h[(long)n * 512 + c]));
  __shared__ float red[4][256];
  red[ty][c] = m;
  __syncthreads();
  if (ty == 0) {
    m = fmaxf(fmaxf(red[0][c], red[1][c]), fmaxf(red[2][c], red[3][c]));
    if (!(m > -INFINITY)) m = 0.f;
    g_pool[g * 1024 + l * 256 + c] = f2bf(m);   // exact: max of bf16 values
  }
}

// ---------------- fc2 + head (reads relu'd fc1 output, writes all outputs) ----------------
__global__ void fc2_head(const u16* __restrict__ fc1out,   // [128][256] bf16, relu applied
                         const u16* __restrict__ W,        // fc2W bf16 [256][18]
                         const u16* __restrict__ b,
                         void* __restrict__ outbuf, const int* __restrict__ flags) {
  int g = blockIdx.x, t = threadIdx.x;
  __shared__ float lr[256];
  __shared__ float ps[144];
  __shared__ float sv[18];
  __shared__ float sred[2];
  float v = bf2f(fc1out[g * 256 + t]);
  lr[t] = v;
  if (flags[0]) ((float*)outbuf)[4608 + g * 256 + t] = v;
  else          ((u16*)outbuf)[4608 + g * 256 + t] = f2bf(v);
  __syncthreads();
  if (t < 144) {
    int o = t % 18, s = t / 18;          // 8 slices of 32 k
    float acc = 0.f;
    int k0 = s * 32;
#pragma unroll 8
    for (int k = k0; k < k0 + 32; k++)
      acc += lr[k] * bf2f(W[k * 18 + o]);
    ps[t] = acc;
  }
  __syncthreads();
  if (t < 18) {
    float acc = bf2f(b[t]);
#pragma unroll
    for (int s = 0; s < 8; s++) acc += ps[s * 18 + t];
    sv[t] = acc;
  }
  __syncthreads();
  if (t == 0) {
    float mx = sv[0];
    for (int i = 1; i < 18; i++) mx = fmaxf(mx, sv[i]);
    float s = 0.f;
    for (int i = 0; i < 18; i++) s += expf(sv[i] - mx);
    sred[0] = mx; sred[1] = logf(s);
  }
  __syncthreads();
  if (t < 18) {
    float raw = sv[t];
    float lsm = raw - sred[0] - sred[1];
    if (flags[0]) {
      ((float*)outbuf)[g * 18 + t] = lsm;
      ((float*)outbuf)[2304 + g * 18 + t] = raw;
    } else {
      ((u16*)outbuf)[g * 18 + t] = f2bf(lsm);
      ((u16*)outbuf)[2304 + g * 18 + t] = f2bf(raw);
    }
  }
}

extern "C" void kernel_launch(void* const* d_in, const int* in_sizes, int n_in,
                              void* d_out, int out_size, void* d_ws, size_t ws_size,
                              hipStream_t stream) {
  (void)in_sizes; (void)n_in; (void)out_size; (void)ws_size;
  const void* x = d_in[0];
  const void* ei = d_in[1];
  const void* batch = d_in[2];
  const void *Wl[4], *bl[4], *Wr[4], *Wm[4], *bm[4];
  for (int l = 0; l < 4; l++) {
    Wl[l] = d_in[3 + l * 5 + 0];
    bl[l] = d_in[3 + l * 5 + 1];
    Wr[l] = d_in[3 + l * 5 + 2];
    Wm[l] = d_in[3 + l * 5 + 3];
    bm[l] = d_in[3 + l * 5 + 4];
  }
  const void* fc1W = d_in[23];
  const void* fc1b = d_in[24];
  const void* fc2W = d_in[25];
  const void* fc2b = d_in[26];

  char* ws = (char*)d_ws;
  size_t off = 0;
  auto alloc = [&](size_t bytes) -> void* {
    void* p = ws + off;
    off = (off + bytes + 255) & ~(size_t)255;
    return p;
  };
  int* flags   = (int*)alloc(16);
  int* row_ptr = (int*)alloc((NN + 1) * sizeof(int));
  int* cursor  = (int*)alloc(NN * sizeof(int));
  int* partial = (int*)alloc(NCHUNK * sizeof(int));
  int* col_src = (int*)alloc((size_t)EE * sizeof(int));
  int* src32   = (int*)alloc((size_t)EE * sizeof(int));
  int* dst32   = (int*)alloc((size_t)EE * sizeof(int));
  int* batch32 = (int*)alloc(NN * sizeof(int));
  int* gs      = (int*)alloc((GG + 1) * sizeof(int));
  u16* WcatT[4]; for (int l = 0; l < 4; l++) WcatT[l] = (u16*)alloc(256 * 512 * 2);
  u16* WmT[4];   for (int l = 0; l < 4; l++) WmT[l]   = (u16*)alloc(256 * 256 * 2);
  u16* bl_bf[4]; for (int l = 0; l < 4; l++) bl_bf[l] = (u16*)alloc(256 * 2);
  u16* bm_bf[4]; for (int l = 0; l < 4; l++) bm_bf[l] = (u16*)alloc(256 * 2);
  u16* fc1WT   = (u16*)alloc(256 * 1024 * 2);
  u16* fc1b_bf = (u16*)alloc(256 * 2);
  u16* fc2W_bf = (u16*)alloc(256 * 18 * 2);
  u16* fc2b_bf = (u16*)alloc(18 * 2);
  u16* x_bf    = (u16*)alloc((size_t)NN * DF * 2);
  u16* Acat    = (u16*)alloc((size_t)NN * 512 * 2);
  u16* tmp     = (u16*)alloc((size_t)NN * 256 * 2);
  u16* gpool   = (u16*)alloc(GG * 1024 * 2);
  u16* fc1out  = (u16*)alloc(GG * 256 * 2);

  hipMemsetAsync(flags, 0, 16, stream);
  detect_kernel<<<256, 256, 0, stream>>>((const u16*)x, (const unsigned*)ei, flags);

  ConvArgs CA; int blk = 0; int si = 0;
  auto addseg = [&](const void* s, u16* d, int n) {
    CA.s[si].src = s; CA.s[si].dst = d; CA.s[si].start_blk = blk; CA.s[si].n = n;
    blk += (n + 255) / 256; si++;
  };
  addseg(x, x_bf, NN * DF);
  addseg(fc2W, fc2W_bf, 256 * 18);
  for (int l = 0; l < 4; l++) addseg(bl[l], bl_bf[l], 256);
  for (int l = 0; l < 4; l++) addseg(bm[l], bm_bf[l], 256);
  addseg(fc1b, fc1b_bf, 256);
  addseg(fc2b, fc2b_bf, 18);
  CA.nseg = si;
  conv_many<<<blk, 256, 0, stream>>>(CA, flags);
  conv_idx<<<(EE + 255) / 256, 256, 0, stream>>>(ei, batch, src32, dst32, batch32, flags);

  WPtrs P;
  for (int l = 0; l < 4; l++) {
    P.Wl[l] = Wl[l]; P.Wr[l] = Wr[l]; P.Wm[l] = Wm[l];
    P.WcatT[l] = WcatT[l]; P.WmT[l] = WmT[l];
  }
  P.fc1W = fc1W; P.fc1WT = fc1WT;
  prep_w_kernel<<<5120, 256, 0, stream>>>(P, flags);

  hipMemsetAsync(cursor, 0, NN * sizeof(int), stream);
  hist_kernel<<<(EE + 255) / 256, 256, 0, stream>>>(dst32, cursor, EE);
  chunk_sum_kernel<<<NCHUNK, 256, 0, stream>>>(cursor, partial, NN);
  scan_partial_kernel<<<1, 256, 0, stream>>>(partial, NCHUNK);
  write_rowptr_kernel<<<NCHUNK, 256, 0, stream>>>(cursor, partial, row_ptr, NN);
  scatter_kernel<<<(EE + 255) / 256, 256, 0, stream>>>(src32, dst32, cursor, col_src, EE);
  graph_start_kernel<<<1, 256, 0, stream>>>(batch32, gs, NN);

  int segblocks = (NN + 3) / 4;
  int gemmgrid = (NN + 127) / 128;    // 391

  for (int l = 0; l < 4; l++) {
    if (l == 0) {
      segmax_kernel<2><<<segblocks, 256, 0, stream>>>(x_bf, DF, row_ptr, col_src,
                                                      Acat, 512, Acat + DF, NN);
    } else {
      segmax_kernel<4><<<segblocks, 256, 0, stream>>>(Acat + 256, 512, row_ptr, col_src,
                                                      Acat, 512, (u16*)nullptr, NN);
    }
    int K = (l == 0) ? 256 : 512;
    gemm256<<<gemmgrid, 256, 0, stream>>>(Acat, 512, K, WcatT[l], bl_bf[l], tmp, 256, NN, 0);
    gemm256<<<gemmgrid, 256, 0, stream>>>(tmp, 256, 256, WmT[l], bm_bf[l], Acat + 256, 512, NN, 1);
    pool_kernel<<<GG, 1024, 0, stream>>>(Acat + 256, gs, gpool, l);
  }

  // fc1 as a single 128x256x1024 MFMA tile
  gemm256<<<1, 256, 0, stream>>>(gpool, 1024, 1024, fc1WT, fc1b_bf, fc1out, 256, GG, 1);
  fc2_head<<<GG, 256, 0, stream>>>(fc1out, fc2W_bf, fc2b_bf, d_out, flags);
}

// Round 5
// 720.827 us; speedup vs baseline: 1.3443x; 1.3443x over previous
//
#include <hip/hip_runtime.h>
#include <stdint.h>

#define NN 50000
#define EE 800000
#define GG 128
#define DF 128
#define DE 256
#define NCHUNK ((NN + 255) / 256)   // 196

typedef unsigned short u16;
typedef __bf16 bf16x8 __attribute__((ext_vector_type(8)));
typedef float f32x4 __attribute__((ext_vector_type(4)));

__device__ __forceinline__ float bf2f(u16 u) {
  union { unsigned int i; float f; } x; x.i = ((unsigned int)u) << 16; return x.f;
}
__device__ __forceinline__ u16 f2bf(float f) {
  union { float f; unsigned int i; } x; x.f = f;
  unsigned int i = x.i;
  return (u16)((i + 0x7fffu + ((i >> 16) & 1u)) >> 16);
}

// global -> LDS direct DMA, 16B/lane; LDS dest = wave-uniform base + lane*16 (m97 path)
__device__ __forceinline__ void async16(const void* g, void* l) {
  __builtin_amdgcn_global_load_lds(
      (const __attribute__((address_space(1))) void*)g,
      (__attribute__((address_space(3))) void*)l,
      16, 0, 0);
}

// ---------------- dtype detection ----------------
__global__ void detect_kernel(const u16* __restrict__ xr,
                              const unsigned* __restrict__ ei_words,
                              int* __restrict__ flags) {
  int i = blockIdx.x * 256 + threadIdx.x;
  int found = 0;
  u16 a = xr[i * 2], b = xr[i * 2 + 1];
  if (((a >> 7) & 0xFFu) == 0xFFu) found = 1;
  if (((b >> 7) & 0xFFu) == 0xFFu) found = 1;
  if (__ballot(found)) {
    if ((threadIdx.x & 63) == 0) atomicOr(&flags[0], 1);
  }
  if (blockIdx.x == 0 && threadIdx.x < 64) {
    unsigned w = ei_words[threadIdx.x * 2 + 1];
    if (__ballot(w != 0u)) {
      if (threadIdx.x == 0) atomicOr(&flags[1], 1);
    }
  }
}

// ---------------- input normalization ----------------
struct ConvSeg { const void* src; u16* dst; int start_blk; int n; };
struct ConvArgs { ConvSeg s[13]; int nseg; };

__global__ void conv_many(ConvArgs A, const int* __restrict__ flags) {
  int f32f = flags[0];
  int b = blockIdx.x;
  for (int i = 0; i < A.nseg; i++) {
    int nb = (A.s[i].n + 255) >> 8;
    if (b >= A.s[i].start_blk && b < A.s[i].start_blk + nb) {
      int idx = ((b - A.s[i].start_blk) << 8) + threadIdx.x;
      if (idx < A.s[i].n) {
        u16 v = f32f ? f2bf(((const float*)A.s[i].src)[idx])
                     : ((const u16*)A.s[i].src)[idx];
        A.s[i].dst[idx] = v;
      }
      return;
    }
  }
}

__global__ void conv_idx(const void* __restrict__ ei, const void* __restrict__ batch,
                         int* __restrict__ src32, int* __restrict__ dst32,
                         int* __restrict__ batch32, const int* __restrict__ flags) {
  int i64 = (flags[1] == 0);
  int i = blockIdx.x * blockDim.x + threadIdx.x;
  if (i < EE) {
    int s, d;
    if (i64) {
      s = (int)((const long long*)ei)[i];
      d = (int)((const long long*)ei)[EE + i];
    } else {
      s = ((const int*)ei)[i];
      d = ((const int*)ei)[EE + i];
    }
    src32[i] = min(max(s, 0), NN - 1);
    dst32[i] = min(max(d, 0), NN - 1);
  }
  if (i < NN) {
    int bv = i64 ? (int)((const long long*)batch)[i] : ((const int*)batch)[i];
    batch32[i] = min(max(bv, 0), GG - 1);
  }
}

// ---------------- CSR build ----------------
__global__ void hist_kernel(const int* __restrict__ dst, int* __restrict__ counts, int E) {
  int e = blockIdx.x * blockDim.x + threadIdx.x;
  if (e < E) atomicAdd(&counts[dst[e]], 1);
}

__global__ void chunk_sum_kernel(const int* __restrict__ counts, int* __restrict__ partial, int n) {
  __shared__ int sh[256];
  int i = blockIdx.x * 256 + threadIdx.x;
  sh[threadIdx.x] = (i < n) ? counts[i] : 0;
  __syncthreads();
  for (int off = 128; off > 0; off >>= 1) {
    if (threadIdx.x < off) sh[threadIdx.x] += sh[threadIdx.x + off];
    __syncthreads();
  }
  if (threadIdx.x == 0) partial[blockIdx.x] = sh[0];
}

__global__ void scan_partial_kernel(int* __restrict__ partial, int np) {
  __shared__ int sh[256];
  int tid = threadIdx.x;
  int x = (tid < np) ? partial[tid] : 0;
  sh[tid] = x;
  __syncthreads();
  for (int off = 1; off < 256; off <<= 1) {
    int v = (tid >= off) ? sh[tid - off] : 0;
    __syncthreads();
    sh[tid] += v;
    __syncthreads();
  }
  if (tid < np) partial[tid] = sh[tid] - x;
}

__global__ void write_rowptr_kernel(int* __restrict__ counts, const int* __restrict__ partial,
                                    int* __restrict__ row_ptr, int n) {
  __shared__ int sh[256];
  int tid = threadIdx.x;
  int i = blockIdx.x * 256 + tid;
  int x = (i < n) ? counts[i] : 0;
  sh[tid] = x;
  __syncthreads();
  for (int off = 1; off < 256; off <<= 1) {
    int v = (tid >= off) ? sh[tid - off] : 0;
    __syncthreads();
    sh[tid] += v;
    __syncthreads();
  }
  int base = partial[blockIdx.x];
  if (i < n) {
    row_ptr[i + 1] = base + sh[tid];
    counts[i] = base + sh[tid] - x;
  }
  if (i == 0) row_ptr[0] = 0;
}

__global__ void scatter_kernel(const int* __restrict__ srcA, const int* __restrict__ dstA,
                               int* __restrict__ cursor, int* __restrict__ col_src, int E) {
  int e = blockIdx.x * blockDim.x + threadIdx.x;
  if (e < E) {
    int slot = atomicAdd(&cursor[dstA[e]], 1);
    col_src[slot] = srcA[e];
  }
}

__global__ void graph_start_kernel(const int* __restrict__ batch, int* __restrict__ gs, int n) {
  int g = threadIdx.x;
  if (g > GG) return;
  int lo = 0, hi = n;
  while (lo < hi) { int mid = (lo + hi) >> 1; if (batch[mid] < g) lo = mid + 1; else hi = mid; }
  gs[g] = lo;
}

// ---------------- weight prep ----------------
__device__ __forceinline__ u16 ldw(const void* p, int idx, int f) {
  return f ? f2bf(((const float*)p)[idx]) : ((const u16*)p)[idx];
}

struct WPtrs {
  const void* Wl[4]; const void* Wr[4]; const void* Wm[4]; const void* fc1W;
  u16* WcatT[4]; u16* WmT[4]; u16* fc1WT;
};

__global__ void prep_w_kernel(WPtrs P, const int* __restrict__ flags) {
  int f = flags[0];
  if (blockIdx.x >= 4096) {
    int idx = ((blockIdx.x - 4096) << 8) + threadIdx.x;   // fc1W^T [256][1024]
    int n = idx >> 10, k = idx & 1023;
    P.fc1WT[idx] = ldw(P.fc1W, k * 256 + n, f);
    return;
  }
  int seg = blockIdx.x >> 9;
  int idx = ((blockIdx.x & 511) << 8) + threadIdx.x;
  if (seg < 4) {
    int l = seg;
    int din = (l == 0) ? DF : DE;
    int K = 2 * din;
    if (idx < 256 * K) {
      int n = idx / K, k = idx - n * K;
      u16 v = (k < din) ? ldw(P.Wl[l], k * 256 + n, f) : ldw(P.Wr[l], (k - din) * 256 + n, f);
      P.WcatT[l][idx] = v;
    }
  } else {
    int l = seg - 4;
    if (idx < 256 * 256) {
      int n = idx >> 8, k = idx & 255;
      P.WmT[l][idx] = ldw(P.Wm[l], k * 256 + n, f);
    }
  }
}

// ---------------- per-node max aggregation ----------------
// LPR lanes cover one row (LPR*16 bytes); R = 64/LPR edges in flight per load wave.
// DF=128 dims -> LPR=16 (R=4); DE=256 dims -> LPR=32 (R=2). 2x unroll => 2R rows in flight.
template <int LPR>
__global__ __launch_bounds__(256) void segmax_kernel(
    const u16* __restrict__ feat, int fstride,
    const int* __restrict__ row_ptr, const int* __restrict__ col_src,
    u16* __restrict__ agg_out, int ostride,
    u16* __restrict__ copy_dst, int n) {
  constexpr int R = 64 / LPR;
  int node = blockIdx.x * 4 + (threadIdx.x >> 6);
  if (node >= n) return;
  int lane = threadIdx.x & 63;
  int sub = lane / LPR;          // which edge in the group
  int cp = lane % LPR;           // 8-dim chunk within the row
  int beg = row_ptr[node], end = row_ptr[node + 1];
  float m[8];
#pragma unroll
  for (int j = 0; j < 8; j++) m[j] = -INFINITY;
  const u16* fb = feat + cp * 8;

  int e = beg + sub;
  for (; e + R < end; e += 2 * R) {
    int s0 = col_src[e];
    int s1 = col_src[e + R];
    bf16x8 v0 = *(const bf16x8*)(fb + (long)s0 * fstride);
    bf16x8 v1 = *(const bf16x8*)(fb + (long)s1 * fstride);
#pragma unroll
    for (int j = 0; j < 8; j++)
      m[j] = fmaxf(m[j], fmaxf((float)v0[j], (float)v1[j]));
  }
  if (e < end) {
    int s0 = col_src[e];
    bf16x8 v0 = *(const bf16x8*)(fb + (long)s0 * fstride);
#pragma unroll
    for (int j = 0; j < 8; j++)
      m[j] = fmaxf(m[j], (float)v0[j]);
  }

  // merge subgroups (identical dim mapping, xor masks multiples of LPR)
#pragma unroll
  for (int d = LPR; d < 64; d <<= 1)
#pragma unroll
    for (int j = 0; j < 8; j++)
      m[j] = fmaxf(m[j], __shfl_xor(m[j], d));

  if (beg == end) {
#pragma unroll
    for (int j = 0; j < 8; j++) m[j] = 0.f;   // empty segment -> 0 (PyG)
  }

  if (sub == 0) {
    union { u16 u[8]; uint4 v; } o;
#pragma unroll
    for (int j = 0; j < 8; j++) o.u[j] = f2bf(m[j]);
    *(uint4*)(agg_out + (long)node * ostride + cp * 8) = o.v;
  }
  if (copy_dst && lane < fstride / 8) {   // layer 0: copy x row alongside agg
    *(uint4*)(copy_dst + (long)node * ostride + lane * 8) =
        *(const uint4*)(feat + (long)node * fstride + lane * 8);
  }
}

// ---------------- MFMA GEMM (m97 structure): C[M,N128*2] = op(A @ B + bias) ----------------
// grid = Mtiles*2; BT is B^T [256][K]; 128x128 tile, 4 waves, 4x4 16x16x32 frags,
// global_load_lds width-16 staging.
__global__ __launch_bounds__(256) void gemm128(
    const u16* __restrict__ A, int lda, int K,
    const u16* __restrict__ BT,
    const u16* __restrict__ bias,
    u16* __restrict__ C, int ldc,
    int M, int relu_flag) {
  __shared__ u16 lsA[128 * 32];
  __shared__ u16 lsB[128 * 32];
  int tid = threadIdx.x;
  int lane = tid & 63, w = tid >> 6;
  int bm = blockIdx.x >> 1, bn = blockIdx.x & 1;
  int wm = (w & 1) << 6, wn = (w >> 1) << 6;
  int ln15 = lane & 15, quad = lane >> 4;

  f32x4 acc[4][4] = {};

  int cm = lane >> 2;          // row within 16-row chunk
  int ck = (lane & 3) << 3;    // col: 8 bf16 = 16B per lane => LDS offset = lane*16B

  int mA0 = min(bm * 128 + w * 16 + cm, M - 1);
  int mA1 = min(bm * 128 + (w + 4) * 16 + cm, M - 1);
  const u16* gA0 = A + (long)mA0 * lda + ck;
  const u16* gA1 = A + (long)mA1 * lda + ck;
  const u16* gB0 = BT + (long)(bn * 128 + w * 16 + cm) * K + ck;
  const u16* gB1 = BT + (long)(bn * 128 + (w + 4) * 16 + cm) * K + ck;
  u16* lA0 = lsA + w * 512;
  u16* lA1 = lsA + (w + 4) * 512;
  u16* lB0 = lsB + w * 512;
  u16* lB1 = lsB + (w + 4) * 512;

  for (int k0 = 0; k0 < K; k0 += 32) {
    async16(gA0 + k0, lA0);
    async16(gA1 + k0, lA1);
    async16(gB0 + k0, lB0);
    async16(gB1 + k0, lB1);
    __syncthreads();   // drains vmcnt: DMA data visible, all waves arrived
    bf16x8 af[4], bfr[4];
#pragma unroll
    for (int t = 0; t < 4; t++) {
      af[t]  = *(const bf16x8*)(lsA + (wm + t * 16 + ln15) * 32 + quad * 8);
      bfr[t] = *(const bf16x8*)(lsB + (wn + t * 16 + ln15) * 32 + quad * 8);
    }
#pragma unroll
    for (int mt = 0; mt < 4; mt++)
#pragma unroll
      for (int nt = 0; nt < 4; nt++)
        acc[mt][nt] = __builtin_amdgcn_mfma_f32_16x16x32_bf16(af[mt], bfr[nt], acc[mt][nt], 0, 0, 0);
    __syncthreads();   // readers done before next iter's DMA overwrites
  }

  float bv[4];
#pragma unroll
  for (int nt = 0; nt < 4; nt++)
    bv[nt] = bf2f(bias[bn * 128 + wn + nt * 16 + ln15]);

#pragma unroll
  for (int mt = 0; mt < 4; mt++) {
    int row0 = bm * 128 + wm + mt * 16 + quad * 4;
#pragma unroll
    for (int r = 0; r < 4; r++) {
      int row = row0 + r;
      if (row < M) {
#pragma unroll
        for (int nt = 0; nt < 4; nt++) {
          float v = acc[mt][nt][r] + bv[nt];
          if (relu_flag) v = fmaxf(v, 0.f);
          C[(long)row * ldc + bn * 128 + wn + nt * 16 + ln15] = f2bf(v);
        }
      }
    }
  }
}

// ---------------- per-layer global max pool (2 blocks per graph) ----------------
__global__ void pool_kernel(const u16* __restrict__ h, const int* __restrict__ gs,
                            u16* __restrict__ g_pool, int l) {
  int g = blockIdx.x >> 1, half = blockIdx.x & 1;
  int c = threadIdx.x & 127, ty = threadIdx.x >> 7;   // 8 row-strides x 128 channels
  int beg = gs[g], end = gs[g + 1];
  float m = -INFINITY;
  const u16* hp = h + half * 128 + c;
  for (int n = beg + ty; n < end; n += 8)
    m = fmaxf(m, bf2f(hp[(long)n * 512]));
  __shared__ float red[8][128];
  red[ty][c] = m;
  __syncthreads();
  if (ty == 0) {
#pragma unroll
    for (int s = 1; s < 8; s++) m = fmaxf(m, red[s][c]);
    if (!(m > -INFINITY)) m = 0.f;
    g_pool[g * 1024 + l * 256 + half * 128 + c] = f2bf(m);   // exact: max of bf16
  }
}

// ---------------- fc2 + head ----------------
__global__ void fc2_head(const u16* __restrict__ fc1out,   // [128][256] bf16, relu applied
                         const u16* __restrict__ W,        // fc2W bf16 [256][18]
                         const u16* __restrict__ b,
                         void* __restrict__ outbuf, const int* __restrict__ flags) {
  int g = blockIdx.x, t = threadIdx.x;
  __shared__ float lr[256];
  __shared__ float ps[144];
  __shared__ float sv[18];
  __shared__ float sred[2];
  float v = bf2f(fc1out[g * 256 + t]);
  lr[t] = v;
  if (flags[0]) ((float*)outbuf)[4608 + g * 256 + t] = v;
  else          ((u16*)outbuf)[4608 + g * 256 + t] = f2bf(v);
  __syncthreads();
  if (t < 144) {
    int o = t % 18, s = t / 18;
    float acc = 0.f;
    int k0 = s * 32;
#pragma unroll 8
    for (int k = k0; k < k0 + 32; k++)
      acc += lr[k] * bf2f(W[k * 18 + o]);
    ps[t] = acc;
  }
  __syncthreads();
  if (t < 18) {
    float acc = bf2f(b[t]);
#pragma unroll
    for (int s = 0; s < 8; s++) acc += ps[s * 18 + t];
    sv[t] = acc;
  }
  __syncthreads();
  if (t == 0) {
    float mx = sv[0];
    for (int i = 1; i < 18; i++) mx = fmaxf(mx, sv[i]);
    float s = 0.f;
    for (int i = 0; i < 18; i++) s += expf(sv[i] - mx);
    sred[0] = mx; sred[1] = logf(s);
  }
  __syncthreads();
  if (t < 18) {
    float raw = sv[t];
    float lsm = raw - sred[0] - sred[1];
    if (flags[0]) {
      ((float*)outbuf)[g * 18 + t] = lsm;
      ((float*)outbuf)[2304 + g * 18 + t] = raw;
    } else {
      ((u16*)outbuf)[g * 18 + t] = f2bf(lsm);
      ((u16*)outbuf)[2304 + g * 18 + t] = f2bf(raw);
    }
  }
}

extern "C" void kernel_launch(void* const* d_in, const int* in_sizes, int n_in,
                              void* d_out, int out_size, void* d_ws, size_t ws_size,
                              hipStream_t stream) {
  (void)in_sizes; (void)n_in; (void)out_size; (void)ws_size;
  const void* x = d_in[0];
  const void* ei = d_in[1];
  const void* batch = d_in[2];
  const void *Wl[4], *bl[4], *Wr[4], *Wm[4], *bm[4];
  for (int l = 0; l < 4; l++) {
    Wl[l] = d_in[3 + l * 5 + 0];
    bl[l] = d_in[3 + l * 5 + 1];
    Wr[l] = d_in[3 + l * 5 + 2];
    Wm[l] = d_in[3 + l * 5 + 3];
    bm[l] = d_in[3 + l * 5 + 4];
  }
  const void* fc1W = d_in[23];
  const void* fc1b = d_in[24];
  const void* fc2W = d_in[25];
  const void* fc2b = d_in[26];

  char* ws = (char*)d_ws;
  size_t off = 0;
  auto alloc = [&](size_t bytes) -> void* {
    void* p = ws + off;
    off = (off + bytes + 255) & ~(size_t)255;
    return p;
  };
  int* flags   = (int*)alloc(16);
  int* row_ptr = (int*)alloc((NN + 1) * sizeof(int));
  int* cursor  = (int*)alloc(NN * sizeof(int));
  int* partial = (int*)alloc(NCHUNK * sizeof(int));
  int* col_src = (int*)alloc((size_t)EE * sizeof(int));
  int* src32   = (int*)alloc((size_t)EE * sizeof(int));
  int* dst32   = (int*)alloc((size_t)EE * sizeof(int));
  int* batch32 = (int*)alloc(NN * sizeof(int));
  int* gs      = (int*)alloc((GG + 1) * sizeof(int));
  u16* WcatT[4]; for (int l = 0; l < 4; l++) WcatT[l] = (u16*)alloc(256 * 512 * 2);
  u16* WmT[4];   for (int l = 0; l < 4; l++) WmT[l]   = (u16*)alloc(256 * 256 * 2);
  u16* bl_bf[4]; for (int l = 0; l < 4; l++) bl_bf[l] = (u16*)alloc(256 * 2);
  u16* bm_bf[4]; for (int l = 0; l < 4; l++) bm_bf[l] = (u16*)alloc(256 * 2);
  u16* fc1WT   = (u16*)alloc(256 * 1024 * 2);
  u16* fc1b_bf = (u16*)alloc(256 * 2);
  u16* fc2W_bf = (u16*)alloc(256 * 18 * 2);
  u16* fc2b_bf = (u16*)alloc(18 * 2);
  u16* x_bf    = (u16*)alloc((size_t)NN * DF * 2);
  u16* Acat    = (u16*)alloc((size_t)NN * 512 * 2);
  u16* tmp     = (u16*)alloc((size_t)NN * 256 * 2);
  u16* gpool   = (u16*)alloc(GG * 1024 * 2);
  u16* fc1out  = (u16*)alloc(GG * 256 * 2);

  hipMemsetAsync(flags, 0, 16, stream);
  detect_kernel<<<256, 256, 0, stream>>>((const u16*)x, (const unsigned*)ei, flags);

  ConvArgs CA; int blk = 0; int si = 0;
  auto addseg = [&](const void* s, u16* d, int n) {
    CA.s[si].src = s; CA.s[si].dst = d; CA.s[si].start_blk = blk; CA.s[si].n = n;
    blk += (n + 255) / 256; si++;
  };
  addseg(x, x_bf, NN * DF);
  addseg(fc2W, fc2W_bf, 256 * 18);
  for (int l = 0; l < 4; l++) addseg(bl[l], bl_bf[l], 256);
  for (int l = 0; l < 4; l++) addseg(bm[l], bm_bf[l], 256);
  addseg(fc1b, fc1b_bf, 256);
  addseg(fc2b, fc2b_bf, 18);
  CA.nseg = si;
  conv_many<<<blk, 256, 0, stream>>>(CA, flags);
  conv_idx<<<(EE + 255) / 256, 256, 0, stream>>>(ei, batch, src32, dst32, batch32, flags);

  WPtrs P;
  for (int l = 0; l < 4; l++) {
    P.Wl[l] = Wl[l]; P.Wr[l] = Wr[l]; P.Wm[l] = Wm[l];
    P.WcatT[l] = WcatT[l]; P.WmT[l] = WmT[l];
  }
  P.fc1W = fc1W; P.fc1WT = fc1WT;
  prep_w_kernel<<<5120, 256, 0, stream>>>(P, flags);

  hipMemsetAsync(cursor, 0, NN * sizeof(int), stream);
  hist_kernel<<<(EE + 255) / 256, 256, 0, stream>>>(dst32, cursor, EE);
  chunk_sum_kernel<<<NCHUNK, 256, 0, stream>>>(cursor, partial, NN);
  scan_partial_kernel<<<1, 256, 0, stream>>>(partial, NCHUNK);
  write_rowptr_kernel<<<NCHUNK, 256, 0, stream>>>(cursor, partial, row_ptr, NN);
  scatter_kernel<<<(EE + 255) / 256, 256, 0, stream>>>(src32, dst32, cursor, col_src, EE);
  graph_start_kernel<<<1, 256, 0, stream>>>(batch32, gs, NN);

  int segblocks = (NN + 3) / 4;
  int gemmgrid = ((NN + 127) / 128) * 2;    // 782

  for (int l = 0; l < 4; l++) {
    if (l == 0) {
      segmax_kernel<16><<<segblocks, 256, 0, stream>>>(x_bf, DF, row_ptr, col_src,
                                                       Acat, 512, Acat + DF, NN);
    } else {
      segmax_kernel<32><<<segblocks, 256, 0, stream>>>(Acat + 256, 512, row_ptr, col_src,
                                                       Acat, 512, (u16*)nullptr, NN);
    }
    int K = (l == 0) ? 256 : 512;
    gemm128<<<gemmgrid, 256, 0, stream>>>(Acat, 512, K, WcatT[l], bl_bf[l], tmp, 256, NN, 0);
    gemm128<<<gemmgrid, 256, 0, stream>>>(tmp, 256, 256, WmT[l], bm_bf[l], Acat + 256, 512, NN, 1);
    pool_kernel<<<GG * 2, 1024, 0, stream>>>(Acat + 256, gs, gpool, l);
  }

  // fc1: 128x256x1024 via the same GEMM (1 M-tile x 2 N-tiles)
  gemm128<<<2, 256, 0, stream>>>(gpool, 1024, 1024, fc1WT, fc1b_bf, fc1out, 256, GG, 1);
  fc2_head<<<GG, 256, 0, stream>>>(fc1out, fc2W_bf, fc2b_bf, d_out, flags);
}

// Round 6
// 698.873 us; speedup vs baseline: 1.3865x; 1.0314x over previous
//
#include <hip/hip_runtime.h>
#include <stdint.h>

#define NN 50000
#define EE 800000
#define GG 128
#define DF 128
#define DE 256
#define NCHUNK ((NN + 255) / 256)   // 196

typedef unsigned short u16;
typedef __bf16 bf16x8 __attribute__((ext_vector_type(8)));
typedef float f32x4 __attribute__((ext_vector_type(4)));
typedef short s16x8 __attribute__((ext_vector_type(8)));

__device__ __forceinline__ float bf2f(u16 u) {
  union { unsigned int i; float f; } x; x.i = ((unsigned int)u) << 16; return x.f;
}
__device__ __forceinline__ u16 f2bf(float f) {
  union { float f; unsigned int i; } x; x.f = f;
  unsigned int i = x.i;
  return (u16)((i + 0x7fffu + ((i >> 16) & 1u)) >> 16);
}

// global -> LDS direct DMA, 16B/lane; LDS dest = wave-uniform base + lane*16 (m97 path)
__device__ __forceinline__ void async16(const void* g, void* l) {
  __builtin_amdgcn_global_load_lds(
      (const __attribute__((address_space(1))) void*)g,
      (__attribute__((address_space(3))) void*)l,
      16, 0, 0);
}

__device__ __forceinline__ s16x8 vmax8(s16x8 a, s16x8 b) {
  return __builtin_elementwise_max(a, b);   // v_pk_max_i16 / v_max_i16
}

// ---------------- dtype detection ----------------
__global__ void detect_kernel(const u16* __restrict__ xr,
                              const unsigned* __restrict__ ei_words,
                              int* __restrict__ flags) {
  int i = blockIdx.x * 256 + threadIdx.x;
  int found = 0;
  u16 a = xr[i * 2], b = xr[i * 2 + 1];
  if (((a >> 7) & 0xFFu) == 0xFFu) found = 1;
  if (((b >> 7) & 0xFFu) == 0xFFu) found = 1;
  if (__ballot(found)) {
    if ((threadIdx.x & 63) == 0) atomicOr(&flags[0], 1);
  }
  if (blockIdx.x == 0 && threadIdx.x < 64) {
    unsigned w = ei_words[threadIdx.x * 2 + 1];
    if (__ballot(w != 0u)) {
      if (threadIdx.x == 0) atomicOr(&flags[1], 1);
    }
  }
}

// ---------------- input normalization ----------------
struct ConvSeg { const void* src; u16* dst; int start_blk; int n; };
struct ConvArgs { ConvSeg s[13]; int nseg; };

__global__ void conv_many(ConvArgs A, const int* __restrict__ flags) {
  int f32f = flags[0];
  int b = blockIdx.x;
  for (int i = 0; i < A.nseg; i++) {
    int nb = (A.s[i].n + 255) >> 8;
    if (b >= A.s[i].start_blk && b < A.s[i].start_blk + nb) {
      int idx = ((b - A.s[i].start_blk) << 8) + threadIdx.x;
      if (idx < A.s[i].n) {
        u16 v = f32f ? f2bf(((const float*)A.s[i].src)[idx])
                     : ((const u16*)A.s[i].src)[idx];
        A.s[i].dst[idx] = v;
      }
      return;
    }
  }
}

// x -> Acat[:,128:256] (bf16) and xk (keyed i16, monotonic under signed compare)
__global__ void conv_x_kernel(const void* __restrict__ x, u16* __restrict__ acat_x,
                              u16* __restrict__ xk, const int* __restrict__ flags) {
  int i = blockIdx.x * 256 + threadIdx.x;
  if (i >= NN * DF) return;
  int node = i >> 7, d = i & 127;
  u16 v = flags[0] ? f2bf(((const float*)x)[i]) : ((const u16*)x)[i];
  acat_x[(long)node * 512 + d] = v;
  short s = (short)v;
  xk[i] = (u16)(s ^ ((s >> 15) & 0x7FFF));
}

// index conversion + fused degree histogram
__global__ void conv_idx(const void* __restrict__ ei, const void* __restrict__ batch,
                         int* __restrict__ src32, int* __restrict__ dst32,
                         int* __restrict__ batch32, int* __restrict__ counts,
                         const int* __restrict__ flags) {
  int i64 = (flags[1] == 0);
  int i = blockIdx.x * blockDim.x + threadIdx.x;
  if (i < EE) {
    int s, d;
    if (i64) {
      s = (int)((const long long*)ei)[i];
      d = (int)((const long long*)ei)[EE + i];
    } else {
      s = ((const int*)ei)[i];
      d = ((const int*)ei)[EE + i];
    }
    s = min(max(s, 0), NN - 1);
    d = min(max(d, 0), NN - 1);
    src32[i] = s;
    dst32[i] = d;
    atomicAdd(&counts[d], 1);
  }
  if (i < NN) {
    int bv = i64 ? (int)((const long long*)batch)[i] : ((const int*)batch)[i];
    batch32[i] = min(max(bv, 0), GG - 1);
  }
}

// ---------------- CSR build ----------------
__global__ void chunk_sum_kernel(const int* __restrict__ counts, int* __restrict__ partial, int n) {
  __shared__ int sh[256];
  int i = blockIdx.x * 256 + threadIdx.x;
  sh[threadIdx.x] = (i < n) ? counts[i] : 0;
  __syncthreads();
  for (int off = 128; off > 0; off >>= 1) {
    if (threadIdx.x < off) sh[threadIdx.x] += sh[threadIdx.x + off];
    __syncthreads();
  }
  if (threadIdx.x == 0) partial[blockIdx.x] = sh[0];
}

__global__ void scan_partial_kernel(int* __restrict__ partial, int np) {
  __shared__ int sh[256];
  int tid = threadIdx.x;
  int x = (tid < np) ? partial[tid] : 0;
  sh[tid] = x;
  __syncthreads();
  for (int off = 1; off < 256; off <<= 1) {
    int v = (tid >= off) ? sh[tid - off] : 0;
    __syncthreads();
    sh[tid] += v;
    __syncthreads();
  }
  if (tid < np) partial[tid] = sh[tid] - x;
}

__global__ void write_rowptr_kernel(int* __restrict__ counts, const int* __restrict__ partial,
                                    int* __restrict__ row_ptr, int n) {
  __shared__ int sh[256];
  int tid = threadIdx.x;
  int i = blockIdx.x * 256 + tid;
  int x = (i < n) ? counts[i] : 0;
  sh[tid] = x;
  __syncthreads();
  for (int off = 1; off < 256; off <<= 1) {
    int v = (tid >= off) ? sh[tid - off] : 0;
    __syncthreads();
    sh[tid] += v;
    __syncthreads();
  }
  int base = partial[blockIdx.x];
  if (i < n) {
    row_ptr[i + 1] = base + sh[tid];
    counts[i] = base + sh[tid] - x;
  }
  if (i == 0) row_ptr[0] = 0;
}

__global__ void scatter_kernel(const int* __restrict__ srcA, const int* __restrict__ dstA,
                               int* __restrict__ cursor, int* __restrict__ col_src, int E) {
  int e = blockIdx.x * blockDim.x + threadIdx.x;
  if (e < E) {
    int slot = atomicAdd(&cursor[dstA[e]], 1);
    col_src[slot] = srcA[e];
  }
}

__global__ void graph_start_kernel(const int* __restrict__ batch, int* __restrict__ gs, int n) {
  int g = threadIdx.x;
  if (g > GG) return;
  int lo = 0, hi = n;
  while (lo < hi) { int mid = (lo + hi) >> 1; if (batch[mid] < g) lo = mid + 1; else hi = mid; }
  gs[g] = lo;
}

// ---------------- weight prep ----------------
__device__ __forceinline__ u16 ldw(const void* p, int idx, int f) {
  return f ? f2bf(((const float*)p)[idx]) : ((const u16*)p)[idx];
}

struct WPtrs {
  const void* Wl[4]; const void* Wr[4]; const void* Wm[4]; const void* fc1W;
  u16* WcatT[4]; u16* WmT[4]; u16* fc1WT;
};

__global__ void prep_w_kernel(WPtrs P, const int* __restrict__ flags) {
  int f = flags[0];
  if (blockIdx.x >= 4096) {
    int idx = ((blockIdx.x - 4096) << 8) + threadIdx.x;   // fc1W^T [256][1024]
    int n = idx >> 10, k = idx & 1023;
    P.fc1WT[idx] = ldw(P.fc1W, k * 256 + n, f);
    return;
  }
  int seg = blockIdx.x >> 9;
  int idx = ((blockIdx.x & 511) << 8) + threadIdx.x;
  if (seg < 4) {
    int l = seg;
    int din = (l == 0) ? DF : DE;
    int K = 2 * din;
    if (idx < 256 * K) {
      int n = idx / K, k = idx - n * K;
      u16 v = (k < din) ? ldw(P.Wl[l], k * 256 + n, f) : ldw(P.Wr[l], (k - din) * 256 + n, f);
      P.WcatT[l][idx] = v;
    }
  } else {
    int l = seg - 4;
    if (idx < 256 * 256) {
      int n = idx >> 8, k = idx & 255;
      P.WmT[l][idx] = ldw(P.Wm[l], k * 256 + n, f);
    }
  }
}

// ---------------- per-node max aggregation (packed i16 max) ----------------
// LPR lanes cover one row; R = 64/LPR edges in flight; 2x unroll.
// KEYED: input is keyed (has negatives, layer 0) -> un-key output, empty->0.
// !KEYED: input is non-negative bf16 (relu output) -> i16 compare valid directly, init 0.
template <int LPR, bool KEYED>
__global__ __launch_bounds__(256) void segmax_kernel(
    const u16* __restrict__ feat, int fstride,
    const int* __restrict__ row_ptr, const int* __restrict__ col_src,
    u16* __restrict__ agg_out, int ostride, int n) {
  constexpr int R = 64 / LPR;
  int node = blockIdx.x * 4 + (threadIdx.x >> 6);
  if (node >= n) return;
  int lane = threadIdx.x & 63;
  int sub = lane / LPR;
  int cp = lane % LPR;
  int beg = row_ptr[node], end = row_ptr[node + 1];
  s16x8 m = (s16x8)(short)(KEYED ? (short)0x807F : (short)0);   // keyed(-inf) or 0
  const u16* fb = feat + cp * 8;

  int e = beg + sub;
  for (; e + R < end; e += 2 * R) {
    s16x8 v0 = *(const s16x8*)(fb + (long)col_src[e] * fstride);
    s16x8 v1 = *(const s16x8*)(fb + (long)col_src[e + R] * fstride);
    m = vmax8(m, vmax8(v0, v1));
  }
  if (e < end)
    m = vmax8(m, *(const s16x8*)(fb + (long)col_src[e] * fstride));

  // merge subgroups via register shuffles (xor strides multiples of LPR)
#pragma unroll
  for (int d = LPR; d < 64; d <<= 1) {
    union { s16x8 s; int i[4]; } t;
    t.s = m;
#pragma unroll
    for (int j = 0; j < 4; j++) t.i[j] = __shfl_xor(t.i[j], d);
    m = vmax8(m, t.s);
  }

  if (sub == 0) {
    if (KEYED) {
      if (beg == end) {
        m = (s16x8)(short)0;            // empty segment -> 0 (PyG)
      } else {
        s16x8 sp = (m >> 15) & (short)0x7FFF;
        m = m ^ sp;                     // un-key (self-inverse transform)
      }
    }
    *(s16x8*)(agg_out + (long)node * ostride + cp * 8) = m;
  }
}

// ---------------- MFMA GEMM (m97 structure): 128x128 tile, async16 staging ----------------
__global__ __launch_bounds__(256) void gemm128(
    const u16* __restrict__ A, int lda, int K,
    const u16* __restrict__ BT,
    const u16* __restrict__ bias,
    u16* __restrict__ C, int ldc,
    int M, int relu_flag) {
  __shared__ u16 lsA[128 * 32];
  __shared__ u16 lsB[128 * 32];
  int tid = threadIdx.x;
  int lane = tid & 63, w = tid >> 6;
  int bm = blockIdx.x >> 1, bn = blockIdx.x & 1;
  int wm = (w & 1) << 6, wn = (w >> 1) << 6;
  int ln15 = lane & 15, quad = lane >> 4;

  f32x4 acc[4][4] = {};

  int cm = lane >> 2;
  int ck = (lane & 3) << 3;

  int mA0 = min(bm * 128 + w * 16 + cm, M - 1);
  int mA1 = min(bm * 128 + (w + 4) * 16 + cm, M - 1);
  const u16* gA0 = A + (long)mA0 * lda + ck;
  const u16* gA1 = A + (long)mA1 * lda + ck;
  const u16* gB0 = BT + (long)(bn * 128 + w * 16 + cm) * K + ck;
  const u16* gB1 = BT + (long)(bn * 128 + (w + 4) * 16 + cm) * K + ck;
  u16* lA0 = lsA + w * 512;
  u16* lA1 = lsA + (w + 4) * 512;
  u16* lB0 = lsB + w * 512;
  u16* lB1 = lsB + (w + 4) * 512;

  for (int k0 = 0; k0 < K; k0 += 32) {
    async16(gA0 + k0, lA0);
    async16(gA1 + k0, lA1);
    async16(gB0 + k0, lB0);
    async16(gB1 + k0, lB1);
    __syncthreads();
    bf16x8 af[4], bfr[4];
#pragma unroll
    for (int t = 0; t < 4; t++) {
      af[t]  = *(const bf16x8*)(lsA + (wm + t * 16 + ln15) * 32 + quad * 8);
      bfr[t] = *(const bf16x8*)(lsB + (wn + t * 16 + ln15) * 32 + quad * 8);
    }
#pragma unroll
    for (int mt = 0; mt < 4; mt++)
#pragma unroll
      for (int nt = 0; nt < 4; nt++)
        acc[mt][nt] = __builtin_amdgcn_mfma_f32_16x16x32_bf16(af[mt], bfr[nt], acc[mt][nt], 0, 0, 0);
    __syncthreads();
  }

  float bv[4];
#pragma unroll
  for (int nt = 0; nt < 4; nt++)
    bv[nt] = bf2f(bias[bn * 128 + wn + nt * 16 + ln15]);

#pragma unroll
  for (int mt = 0; mt < 4; mt++) {
    int row0 = bm * 128 + wm + mt * 16 + quad * 4;
#pragma unroll
    for (int r = 0; r < 4; r++) {
      int row = row0 + r;
      if (row < M) {
#pragma unroll
        for (int nt = 0; nt < 4; nt++) {
          float v = acc[mt][nt][r] + bv[nt];
          if (relu_flag) v = fmaxf(v, 0.f);
          C[(long)row * ldc + bn * 128 + wn + nt * 16 + ln15] = f2bf(v);
        }
      }
    }
  }
}

// ---------------- per-layer global max pool (packed i16, 16B loads) ----------------
// h is relu output (>=0) -> i16 max valid, init 0 = empty convention
__global__ void pool_kernel(const u16* __restrict__ h, const int* __restrict__ gs,
                            u16* __restrict__ g_pool, int l) {
  int g = blockIdx.x;
  int chunk = threadIdx.x & 31;      // 32 chunks x 8 ch = 256 channels
  int rg = threadIdx.x >> 5;         // 32 row-groups
  int beg = gs[g], end = gs[g + 1];
  s16x8 m = (s16x8)(short)0;
  const u16* hp = h + chunk * 8;
  for (int n = beg + rg; n < end; n += 32)
    m = vmax8(m, *(const s16x8*)(hp + (long)n * 512));
  __shared__ s16x8 red[32][32];
  red[rg][chunk] = m;
  __syncthreads();
  for (int s = 16; s >= 1; s >>= 1) {
    if (rg < s) red[rg][chunk] = vmax8(red[rg][chunk], red[rg + s][chunk]);
    __syncthreads();
  }
  if (rg == 0)
    *(s16x8*)(g_pool + g * 1024 + l * 256 + chunk * 8) = red[0][chunk];
}

// ---------------- fc2 + head ----------------
__global__ void fc2_head(const u16* __restrict__ fc1out,
                         const u16* __restrict__ W,
                         const u16* __restrict__ b,
                         void* __restrict__ outbuf, const int* __restrict__ flags) {
  int g = blockIdx.x, t = threadIdx.x;
  __shared__ float lr[256];
  __shared__ float ps[144];
  __shared__ float sv[18];
  __shared__ float sred[2];
  float v = bf2f(fc1out[g * 256 + t]);
  lr[t] = v;
  if (flags[0]) ((float*)outbuf)[4608 + g * 256 + t] = v;
  else          ((u16*)outbuf)[4608 + g * 256 + t] = f2bf(v);
  __syncthreads();
  if (t < 144) {
    int o = t % 18, s = t / 18;
    float acc = 0.f;
    int k0 = s * 32;
#pragma unroll 8
    for (int k = k0; k < k0 + 32; k++)
      acc += lr[k] * bf2f(W[k * 18 + o]);
    ps[t] = acc;
  }
  __syncthreads();
  if (t < 18) {
    float acc = bf2f(b[t]);
#pragma unroll
    for (int s = 0; s < 8; s++) acc += ps[s * 18 + t];
    sv[t] = acc;
  }
  __syncthreads();
  if (t == 0) {
    float mx = sv[0];
    for (int i = 1; i < 18; i++) mx = fmaxf(mx, sv[i]);
    float s = 0.f;
    for (int i = 0; i < 18; i++) s += expf(sv[i] - mx);
    sred[0] = mx; sred[1] = logf(s);
  }
  __syncthreads();
  if (t < 18) {
    float raw = sv[t];
    float lsm = raw - sred[0] - sred[1];
    if (flags[0]) {
      ((float*)outbuf)[g * 18 + t] = lsm;
      ((float*)outbuf)[2304 + g * 18 + t] = raw;
    } else {
      ((u16*)outbuf)[g * 18 + t] = f2bf(lsm);
      ((u16*)outbuf)[2304 + g * 18 + t] = f2bf(raw);
    }
  }
}

extern "C" void kernel_launch(void* const* d_in, const int* in_sizes, int n_in,
                              void* d_out, int out_size, void* d_ws, size_t ws_size,
                              hipStream_t stream) {
  (void)in_sizes; (void)n_in; (void)out_size; (void)ws_size;
  const void* x = d_in[0];
  const void* ei = d_in[1];
  const void* batch = d_in[2];
  const void *Wl[4], *bl[4], *Wr[4], *Wm[4], *bm[4];
  for (int l = 0; l < 4; l++) {
    Wl[l] = d_in[3 + l * 5 + 0];
    bl[l] = d_in[3 + l * 5 + 1];
    Wr[l] = d_in[3 + l * 5 + 2];
    Wm[l] = d_in[3 + l * 5 + 3];
    bm[l] = d_in[3 + l * 5 + 4];
  }
  const void* fc1W = d_in[23];
  const void* fc1b = d_in[24];
  const void* fc2W = d_in[25];
  const void* fc2b = d_in[26];

  char* ws = (char*)d_ws;
  size_t off = 0;
  auto alloc = [&](size_t bytes) -> void* {
    void* p = ws + off;
    off = (off + bytes + 255) & ~(size_t)255;
    return p;
  };
  int* flags   = (int*)alloc(16);
  int* row_ptr = (int*)alloc((NN + 1) * sizeof(int));
  int* cursor  = (int*)alloc(NN * sizeof(int));
  int* partial = (int*)alloc(NCHUNK * sizeof(int));
  int* col_src = (int*)alloc((size_t)EE * sizeof(int));
  int* src32   = (int*)alloc((size_t)EE * sizeof(int));
  int* dst32   = (int*)alloc((size_t)EE * sizeof(int));
  int* batch32 = (int*)alloc(NN * sizeof(int));
  int* gs      = (int*)alloc((GG + 1) * sizeof(int));
  u16* WcatT[4]; for (int l = 0; l < 4; l++) WcatT[l] = (u16*)alloc(256 * 512 * 2);
  u16* WmT[4];   for (int l = 0; l < 4; l++) WmT[l]   = (u16*)alloc(256 * 256 * 2);
  u16* bl_bf[4]; for (int l = 0; l < 4; l++) bl_bf[l] = (u16*)alloc(256 * 2);
  u16* bm_bf[4]; for (int l = 0; l < 4; l++) bm_bf[l] = (u16*)alloc(256 * 2);
  u16* fc1WT   = (u16*)alloc(256 * 1024 * 2);
  u16* fc1b_bf = (u16*)alloc(256 * 2);
  u16* fc2W_bf = (u16*)alloc(256 * 18 * 2);
  u16* fc2b_bf = (u16*)alloc(18 * 2);
  u16* xk      = (u16*)alloc((size_t)NN * DF * 2);
  u16* Acat    = (u16*)alloc((size_t)NN * 512 * 2);
  u16* tmp     = (u16*)alloc((size_t)NN * 256 * 2);
  u16* gpool   = (u16*)alloc(GG * 1024 * 2);
  u16* fc1out  = (u16*)alloc(GG * 256 * 2);

  hipMemsetAsync(flags, 0, 16, stream);
  hipMemsetAsync(cursor, 0, NN * sizeof(int), stream);
  detect_kernel<<<256, 256, 0, stream>>>((const u16*)x, (const unsigned*)ei, flags);

  ConvArgs CA; int blk = 0; int si = 0;
  auto addseg = [&](const void* s, u16* d, int n) {
    CA.s[si].src = s; CA.s[si].dst = d; CA.s[si].start_blk = blk; CA.s[si].n = n;
    blk += (n + 255) / 256; si++;
  };
  addseg(fc2W, fc2W_bf, 256 * 18);
  for (int l = 0; l < 4; l++) addseg(bl[l], bl_bf[l], 256);
  for (int l = 0; l < 4; l++) addseg(bm[l], bm_bf[l], 256);
  addseg(fc1b, fc1b_bf, 256);
  addseg(fc2b, fc2b_bf, 18);
  CA.nseg = si;
  conv_many<<<blk, 256, 0, stream>>>(CA, flags);
  conv_x_kernel<<<(NN * DF + 255) / 256, 256, 0, stream>>>(x, Acat + DF, xk, flags);
  conv_idx<<<(EE + 255) / 256, 256, 0, stream>>>(ei, batch, src32, dst32, batch32, cursor, flags);

  WPtrs P;
  for (int l = 0; l < 4; l++) {
    P.Wl[l] = Wl[l]; P.Wr[l] = Wr[l]; P.Wm[l] = Wm[l];
    P.WcatT[l] = WcatT[l]; P.WmT[l] = WmT[l];
  }
  P.fc1W = fc1W; P.fc1WT = fc1WT;
  prep_w_kernel<<<5120, 256, 0, stream>>>(P, flags);

  chunk_sum_kernel<<<NCHUNK, 256, 0, stream>>>(cursor, partial, NN);
  scan_partial_kernel<<<1, 256, 0, stream>>>(partial, NCHUNK);
  write_rowptr_kernel<<<NCHUNK, 256, 0, stream>>>(cursor, partial, row_ptr, NN);
  scatter_kernel<<<(EE + 255) / 256, 256, 0, stream>>>(src32, dst32, cursor, col_src, EE);
  graph_start_kernel<<<1, 256, 0, stream>>>(batch32, gs, NN);

  int segblocks = (NN + 3) / 4;
  int gemmgrid = ((NN + 127) / 128) * 2;    // 782

  for (int l = 0; l < 4; l++) {
    if (l == 0) {
      segmax_kernel<16, true><<<segblocks, 256, 0, stream>>>(xk, DF, row_ptr, col_src,
                                                             Acat, 512, NN);
    } else {
      segmax_kernel<32, false><<<segblocks, 256, 0, stream>>>(Acat + 256, 512, row_ptr, col_src,
                                                              Acat, 512, NN);
    }
    int K = (l == 0) ? 256 : 512;
    gemm128<<<gemmgrid, 256, 0, stream>>>(Acat, 512, K, WcatT[l], bl_bf[l], tmp, 256, NN, 0);
    gemm128<<<gemmgrid, 256, 0, stream>>>(tmp, 256, 256, WmT[l], bm_bf[l], Acat + 256, 512, NN, 1);
    pool_kernel<<<GG, 1024, 0, stream>>>(Acat + 256, gs, gpool, l);
  }

  // fc1: 128x256x1024 via the same GEMM (1 M-tile x 2 N-tiles)
  gemm128<<<2, 256, 0, stream>>>(gpool, 1024, 1024, fc1WT, fc1b_bf, fc1out, 256, GG, 1);
  fc2_head<<<GG, 256, 0, stream>>>(fc1out, fc2W_bf, fc2b_bf, d_out, flags);
}

// Round 7
// 677.471 us; speedup vs baseline: 1.4303x; 1.0316x over previous
//
#include <hip/hip_runtime.h>
#include <stdint.h>

#define NN 50000
#define EE 800000
#define GG 128
#define DF 128
#define DE 256
#define NCHUNK ((NN + 255) / 256)   // 196

typedef unsigned short u16;
typedef __bf16 bf16x8 __attribute__((ext_vector_type(8)));
typedef float f32x4 __attribute__((ext_vector_type(4)));
typedef short s16x8 __attribute__((ext_vector_type(8)));

__device__ __forceinline__ float bf2f(u16 u) {
  union { unsigned int i; float f; } x; x.i = ((unsigned int)u) << 16; return x.f;
}
__device__ __forceinline__ u16 f2bf(float f) {
  union { float f; unsigned int i; } x; x.f = f;
  unsigned int i = x.i;
  return (u16)((i + 0x7fffu + ((i >> 16) & 1u)) >> 16);
}

// global -> LDS direct DMA, 16B/lane; LDS dest = wave-uniform base + lane*16 (m97 path)
__device__ __forceinline__ void async16(const void* g, void* l) {
  __builtin_amdgcn_global_load_lds(
      (const __attribute__((address_space(1))) void*)g,
      (__attribute__((address_space(3))) void*)l,
      16, 0, 0);
}

__device__ __forceinline__ s16x8 vmax8(s16x8 a, s16x8 b) {
  return __builtin_elementwise_max(a, b);   // v_pk_max_i16
}

// ---------------- dtype detection ----------------
__global__ void detect_kernel(const u16* __restrict__ xr,
                              const unsigned* __restrict__ ei_words,
                              int* __restrict__ flags) {
  int i = blockIdx.x * 256 + threadIdx.x;
  int found = 0;
  u16 a = xr[i * 2], b = xr[i * 2 + 1];
  if (((a >> 7) & 0xFFu) == 0xFFu) found = 1;
  if (((b >> 7) & 0xFFu) == 0xFFu) found = 1;
  if (__ballot(found)) {
    if ((threadIdx.x & 63) == 0) atomicOr(&flags[0], 1);
  }
  if (blockIdx.x == 0 && threadIdx.x < 64) {
    unsigned w = ei_words[threadIdx.x * 2 + 1];
    if (__ballot(w != 0u)) {
      if (threadIdx.x == 0) atomicOr(&flags[1], 1);
    }
  }
}

// ---------------- input normalization ----------------
struct ConvSeg { const void* src; u16* dst; int start_blk; int n; };
struct ConvArgs { ConvSeg s[13]; int nseg; };

__global__ void conv_many(ConvArgs A, const int* __restrict__ flags) {
  int f32f = flags[0];
  int b = blockIdx.x;
  for (int i = 0; i < A.nseg; i++) {
    int nb = (A.s[i].n + 255) >> 8;
    if (b >= A.s[i].start_blk && b < A.s[i].start_blk + nb) {
      int idx = ((b - A.s[i].start_blk) << 8) + threadIdx.x;
      if (idx < A.s[i].n) {
        u16 v = f32f ? f2bf(((const float*)A.s[i].src)[idx])
                     : ((const u16*)A.s[i].src)[idx];
        A.s[i].dst[idx] = v;
      }
      return;
    }
  }
}

// x -> Acat[:,128:256] (bf16) and xk (keyed i16, monotonic under signed compare)
__global__ void conv_x_kernel(const void* __restrict__ x, u16* __restrict__ acat_x,
                              u16* __restrict__ xk, const int* __restrict__ flags) {
  int i = blockIdx.x * 256 + threadIdx.x;
  if (i >= NN * DF) return;
  int node = i >> 7, d = i & 127;
  u16 v = flags[0] ? f2bf(((const float*)x)[i]) : ((const u16*)x)[i];
  acat_x[(long)node * 512 + d] = v;
  short s = (short)v;
  xk[i] = (u16)(s ^ ((s >> 15) & 0x7FFF));
}

// index conversion + fused degree histogram
__global__ void conv_idx(const void* __restrict__ ei, const void* __restrict__ batch,
                         int* __restrict__ src32, int* __restrict__ dst32,
                         int* __restrict__ batch32, int* __restrict__ counts,
                         const int* __restrict__ flags) {
  int i64 = (flags[1] == 0);
  int i = blockIdx.x * blockDim.x + threadIdx.x;
  if (i < EE) {
    int s, d;
    if (i64) {
      s = (int)((const long long*)ei)[i];
      d = (int)((const long long*)ei)[EE + i];
    } else {
      s = ((const int*)ei)[i];
      d = ((const int*)ei)[EE + i];
    }
    s = min(max(s, 0), NN - 1);
    d = min(max(d, 0), NN - 1);
    src32[i] = s;
    dst32[i] = d;
    atomicAdd(&counts[d], 1);
  }
  if (i < NN) {
    int bv = i64 ? (int)((const long long*)batch)[i] : ((const int*)batch)[i];
    batch32[i] = min(max(bv, 0), GG - 1);
  }
}

// ---------------- CSR build ----------------
__global__ void chunk_sum_kernel(const int* __restrict__ counts, int* __restrict__ partial, int n) {
  __shared__ int sh[256];
  int i = blockIdx.x * 256 + threadIdx.x;
  sh[threadIdx.x] = (i < n) ? counts[i] : 0;
  __syncthreads();
  for (int off = 128; off > 0; off >>= 1) {
    if (threadIdx.x < off) sh[threadIdx.x] += sh[threadIdx.x + off];
    __syncthreads();
  }
  if (threadIdx.x == 0) partial[blockIdx.x] = sh[0];
}

// exclusive scan of partials + graph starts (fused: both tiny single-block jobs)
__global__ void scan_partial_kernel(int* __restrict__ partial, int np,
                                    const int* __restrict__ batch, int* __restrict__ gs, int n) {
  __shared__ int sh[256];
  int tid = threadIdx.x;
  int x = (tid < np) ? partial[tid] : 0;
  sh[tid] = x;
  __syncthreads();
  for (int off = 1; off < 256; off <<= 1) {
    int v = (tid >= off) ? sh[tid - off] : 0;
    __syncthreads();
    sh[tid] += v;
    __syncthreads();
  }
  if (tid < np) partial[tid] = sh[tid] - x;
  if (tid <= GG) {
    int lo = 0, hi = n;
    while (lo < hi) { int mid = (lo + hi) >> 1; if (batch[mid] < tid) lo = mid + 1; else hi = mid; }
    gs[tid] = lo;
  }
}

__global__ void write_rowptr_kernel(int* __restrict__ counts, const int* __restrict__ partial,
                                    int* __restrict__ row_ptr, int n) {
  __shared__ int sh[256];
  int tid = threadIdx.x;
  int i = blockIdx.x * 256 + tid;
  int x = (i < n) ? counts[i] : 0;
  sh[tid] = x;
  __syncthreads();
  for (int off = 1; off < 256; off <<= 1) {
    int v = (tid >= off) ? sh[tid - off] : 0;
    __syncthreads();
    sh[tid] += v;
    __syncthreads();
  }
  int base = partial[blockIdx.x];
  if (i < n) {
    row_ptr[i + 1] = base + sh[tid];
    counts[i] = base + sh[tid] - x;
  }
  if (i == 0) row_ptr[0] = 0;
}

__global__ void scatter_kernel(const int* __restrict__ srcA, const int* __restrict__ dstA,
                               int* __restrict__ cursor, int* __restrict__ col_src, int E) {
  int e = blockIdx.x * blockDim.x + threadIdx.x;
  if (e < E) {
    int slot = atomicAdd(&cursor[dstA[e]], 1);
    col_src[slot] = srcA[e];
  }
}

// ---------------- weight prep ----------------
__device__ __forceinline__ u16 ldw(const void* p, int idx, int f) {
  return f ? f2bf(((const float*)p)[idx]) : ((const u16*)p)[idx];
}

struct WPtrs {
  const void* Wl[4]; const void* Wr[4]; const void* Wm[4]; const void* fc1W;
  u16* WcatT[4]; u16* WmT[4]; u16* fc1WT;
};

__global__ void prep_w_kernel(WPtrs P, const int* __restrict__ flags) {
  int f = flags[0];
  if (blockIdx.x >= 4096) {
    int idx = ((blockIdx.x - 4096) << 8) + threadIdx.x;   // fc1W^T [256][1024]
    int n = idx >> 10, k = idx & 1023;
    P.fc1WT[idx] = ldw(P.fc1W, k * 256 + n, f);
    return;
  }
  int seg = blockIdx.x >> 9;
  int idx = ((blockIdx.x & 511) << 8) + threadIdx.x;
  if (seg < 4) {
    int l = seg;
    int din = (l == 0) ? DF : DE;
    int K = 2 * din;
    if (idx < 256 * K) {
      int n = idx / K, k = idx - n * K;
      u16 v = (k < din) ? ldw(P.Wl[l], k * 256 + n, f) : ldw(P.Wr[l], (k - din) * 256 + n, f);
      P.WcatT[l][idx] = v;
    }
  } else {
    int l = seg - 4;
    if (idx < 256 * 256) {
      int n = idx >> 8, k = idx & 255;
      P.WmT[l][idx] = ldw(P.Wm[l], k * 256 + n, f);
    }
  }
}

// ---------------- per-node max aggregation (packed i16 max, 4-deep ILP) ----------------
template <int LPR, bool KEYED>
__global__ __launch_bounds__(256) void segmax_kernel(
    const u16* __restrict__ feat, int fstride,
    const int* __restrict__ row_ptr, const int* __restrict__ col_src,
    u16* __restrict__ agg_out, int ostride, int n) {
  constexpr int R = 64 / LPR;
  int node = blockIdx.x * 4 + (threadIdx.x >> 6);
  if (node >= n) return;
  int lane = threadIdx.x & 63;
  int sub = lane / LPR;
  int cp = lane % LPR;
  int beg = row_ptr[node], end = row_ptr[node + 1];
  s16x8 m = (s16x8)(short)(KEYED ? (short)0x807F : (short)0);
  const u16* fb = feat + cp * 8;

  int e = beg + sub;
  // 4-deep unroll: 4 independent index loads, then 4 independent row gathers
  for (; e + 3 * R < end; e += 4 * R) {
    int s0 = col_src[e];
    int s1 = col_src[e + R];
    int s2 = col_src[e + 2 * R];
    int s3 = col_src[e + 3 * R];
    s16x8 v0 = *(const s16x8*)(fb + (long)s0 * fstride);
    s16x8 v1 = *(const s16x8*)(fb + (long)s1 * fstride);
    s16x8 v2 = *(const s16x8*)(fb + (long)s2 * fstride);
    s16x8 v3 = *(const s16x8*)(fb + (long)s3 * fstride);
    m = vmax8(m, vmax8(vmax8(v0, v1), vmax8(v2, v3)));
  }
  for (; e < end; e += R)
    m = vmax8(m, *(const s16x8*)(fb + (long)col_src[e] * fstride));

  // merge subgroups via register shuffles
#pragma unroll
  for (int d = LPR; d < 64; d <<= 1) {
    union { s16x8 s; int i[4]; } t;
    t.s = m;
#pragma unroll
    for (int j = 0; j < 4; j++) t.i[j] = __shfl_xor(t.i[j], d);
    m = vmax8(m, t.s);
  }

  if (sub == 0) {
    if (KEYED) {
      if (beg == end) {
        m = (s16x8)(short)0;            // empty segment -> 0 (PyG)
      } else {
        s16x8 sp = (m >> 15) & (short)0x7FFF;
        m = m ^ sp;                     // un-key
      }
    }
    *(s16x8*)(agg_out + (long)node * ostride + cp * 8) = m;
  }
}

// ---------------- MFMA GEMM (m97 structure): 128x128 tile, async16 staging ----------------
__global__ __launch_bounds__(256) void gemm128(
    const u16* __restrict__ A, int lda, int K,
    const u16* __restrict__ BT,
    const u16* __restrict__ bias,
    u16* __restrict__ C, int ldc,
    int M, int relu_flag) {
  __shared__ u16 lsA[128 * 32];
  __shared__ u16 lsB[128 * 32];
  int tid = threadIdx.x;
  int lane = tid & 63, w = tid >> 6;
  int bm = blockIdx.x >> 1, bn = blockIdx.x & 1;
  int wm = (w & 1) << 6, wn = (w >> 1) << 6;
  int ln15 = lane & 15, quad = lane >> 4;

  f32x4 acc[4][4] = {};

  int cm = lane >> 2;
  int ck = (lane & 3) << 3;

  int mA0 = min(bm * 128 + w * 16 + cm, M - 1);
  int mA1 = min(bm * 128 + (w + 4) * 16 + cm, M - 1);
  const u16* gA0 = A + (long)mA0 * lda + ck;
  const u16* gA1 = A + (long)mA1 * lda + ck;
  const u16* gB0 = BT + (long)(bn * 128 + w * 16 + cm) * K + ck;
  const u16* gB1 = BT + (long)(bn * 128 + (w + 4) * 16 + cm) * K + ck;
  u16* lA0 = lsA + w * 512;
  u16* lA1 = lsA + (w + 4) * 512;
  u16* lB0 = lsB + w * 512;
  u16* lB1 = lsB + (w + 4) * 512;

  for (int k0 = 0; k0 < K; k0 += 32) {
    async16(gA0 + k0, lA0);
    async16(gA1 + k0, lA1);
    async16(gB0 + k0, lB0);
    async16(gB1 + k0, lB1);
    __syncthreads();
    bf16x8 af[4], bfr[4];
#pragma unroll
    for (int t = 0; t < 4; t++) {
      af[t]  = *(const bf16x8*)(lsA + (wm + t * 16 + ln15) * 32 + quad * 8);
      bfr[t] = *(const bf16x8*)(lsB + (wn + t * 16 + ln15) * 32 + quad * 8);
    }
#pragma unroll
    for (int mt = 0; mt < 4; mt++)
#pragma unroll
      for (int nt = 0; nt < 4; nt++)
        acc[mt][nt] = __builtin_amdgcn_mfma_f32_16x16x32_bf16(af[mt], bfr[nt], acc[mt][nt], 0, 0, 0);
    __syncthreads();
  }

  float bv[4];
#pragma unroll
  for (int nt = 0; nt < 4; nt++)
    bv[nt] = bf2f(bias[bn * 128 + wn + nt * 16 + ln15]);

#pragma unroll
  for (int mt = 0; mt < 4; mt++) {
    int row0 = bm * 128 + wm + mt * 16 + quad * 4;
#pragma unroll
    for (int r = 0; r < 4; r++) {
      int row = row0 + r;
      if (row < M) {
#pragma unroll
        for (int nt = 0; nt < 4; nt++) {
          float v = acc[mt][nt][r] + bv[nt];
          if (relu_flag) v = fmaxf(v, 0.f);
          C[(long)row * ldc + bn * 128 + wn + nt * 16 + ln15] = f2bf(v);
        }
      }
    }
  }
}

// ---------------- fc1 split-K GEMM: Cpart[slice][128][256] f32 partials ----------------
// grid = 8: slice = blockIdx>>1 (K window of 256), bn = blockIdx&1 (N half)
__global__ __launch_bounds__(256) void fc1_gemm(
    const u16* __restrict__ A,      // gpool [128][1024]
    const u16* __restrict__ BT,     // fc1WT [256][1024]
    float* __restrict__ Cpart) {
  __shared__ u16 lsA[128 * 32];
  __shared__ u16 lsB[128 * 32];
  int tid = threadIdx.x;
  int lane = tid & 63, w = tid >> 6;
  int slice = blockIdx.x >> 1, bn = blockIdx.x & 1;
  int wm = (w & 1) << 6, wn = (w >> 1) << 6;
  int ln15 = lane & 15, quad = lane >> 4;

  f32x4 acc[4][4] = {};

  int cm = lane >> 2;
  int ck = (lane & 3) << 3;
  int kb = slice * 256;

  const u16* gA0 = A + (long)(w * 16 + cm) * 1024 + kb + ck;
  const u16* gA1 = A + (long)((w + 4) * 16 + cm) * 1024 + kb + ck;
  const u16* gB0 = BT + (long)(bn * 128 + w * 16 + cm) * 1024 + kb + ck;
  const u16* gB1 = BT + (long)(bn * 128 + (w + 4) * 16 + cm) * 1024 + kb + ck;
  u16* lA0 = lsA + w * 512;
  u16* lA1 = lsA + (w + 4) * 512;
  u16* lB0 = lsB + w * 512;
  u16* lB1 = lsB + (w + 4) * 512;

  for (int k0 = 0; k0 < 256; k0 += 32) {
    async16(gA0 + k0, lA0);
    async16(gA1 + k0, lA1);
    async16(gB0 + k0, lB0);
    async16(gB1 + k0, lB1);
    __syncthreads();
    bf16x8 af[4], bfr[4];
#pragma unroll
    for (int t = 0; t < 4; t++) {
      af[t]  = *(const bf16x8*)(lsA + (wm + t * 16 + ln15) * 32 + quad * 8);
      bfr[t] = *(const bf16x8*)(lsB + (wn + t * 16 + ln15) * 32 + quad * 8);
    }
#pragma unroll
    for (int mt = 0; mt < 4; mt++)
#pragma unroll
      for (int nt = 0; nt < 4; nt++)
        acc[mt][nt] = __builtin_amdgcn_mfma_f32_16x16x32_bf16(af[mt], bfr[nt], acc[mt][nt], 0, 0, 0);
    __syncthreads();
  }

  float* Cb = Cpart + slice * (GG * 256);
#pragma unroll
  for (int mt = 0; mt < 4; mt++) {
    int row0 = wm + mt * 16 + quad * 4;
#pragma unroll
    for (int r = 0; r < 4; r++)
#pragma unroll
      for (int nt = 0; nt < 4; nt++)
        Cb[(row0 + r) * 256 + bn * 128 + wn + nt * 16 + ln15] = acc[mt][nt][r];
  }
}

// ---------------- per-layer global max pool (packed i16, 16B loads) ----------------
__global__ void pool_kernel(const u16* __restrict__ h, const int* __restrict__ gs,
                            u16* __restrict__ g_pool, int l) {
  int g = blockIdx.x;
  int chunk = threadIdx.x & 31;
  int rg = threadIdx.x >> 5;
  int beg = gs[g], end = gs[g + 1];
  s16x8 m = (s16x8)(short)0;
  const u16* hp = h + chunk * 8;
  for (int n = beg + rg; n < end; n += 32)
    m = vmax8(m, *(const s16x8*)(hp + (long)n * 512));
  __shared__ s16x8 red[32][32];
  red[rg][chunk] = m;
  __syncthreads();
  for (int s = 16; s >= 1; s >>= 1) {
    if (rg < s) red[rg][chunk] = vmax8(red[rg][chunk], red[rg + s][chunk]);
    __syncthreads();
  }
  if (rg == 0)
    *(s16x8*)(g_pool + g * 1024 + l * 256 + chunk * 8) = red[0][chunk];
}

// ---------------- fc2 + head (sums fc1 split-K partials) ----------------
__global__ void fc2_head(const float* __restrict__ fc1part,   // [4][128][256] f32
                         const u16* __restrict__ fc1b,
                         const u16* __restrict__ W,            // fc2W bf16 [256][18]
                         const u16* __restrict__ b,
                         void* __restrict__ outbuf, const int* __restrict__ flags) {
  int g = blockIdx.x, t = threadIdx.x;
  __shared__ float lr[256];
  __shared__ float ps[144];
  __shared__ float sv[18];
  __shared__ float sred[2];
  float v = bf2f(fc1b[t]);
#pragma unroll
  for (int s = 0; s < 4; s++) v += fc1part[s * (GG * 256) + g * 256 + t];
  v = fmaxf(v, 0.f);
  lr[t] = v;
  if (flags[0]) ((float*)outbuf)[4608 + g * 256 + t] = v;
  else          ((u16*)outbuf)[4608 + g * 256 + t] = f2bf(v);
  __syncthreads();
  if (t < 144) {
    int o = t % 18, s = t / 18;
    float acc = 0.f;
    int k0 = s * 32;
#pragma unroll 8
    for (int k = k0; k < k0 + 32; k++)
      acc += lr[k] * bf2f(W[k * 18 + o]);
    ps[t] = acc;
  }
  __syncthreads();
  if (t < 18) {
    float acc = bf2f(b[t]);
#pragma unroll
    for (int s = 0; s < 8; s++) acc += ps[s * 18 + t];
    sv[t] = acc;
  }
  __syncthreads();
  if (t == 0) {
    float mx = sv[0];
    for (int i = 1; i < 18; i++) mx = fmaxf(mx, sv[i]);
    float s = 0.f;
    for (int i = 0; i < 18; i++) s += expf(sv[i] - mx);
    sred[0] = mx; sred[1] = logf(s);
  }
  __syncthreads();
  if (t < 18) {
    float raw = sv[t];
    float lsm = raw - sred[0] - sred[1];
    if (flags[0]) {
      ((float*)outbuf)[g * 18 + t] = lsm;
      ((float*)outbuf)[2304 + g * 18 + t] = raw;
    } else {
      ((u16*)outbuf)[g * 18 + t] = f2bf(lsm);
      ((u16*)outbuf)[2304 + g * 18 + t] = f2bf(raw);
    }
  }
}

extern "C" void kernel_launch(void* const* d_in, const int* in_sizes, int n_in,
                              void* d_out, int out_size, void* d_ws, size_t ws_size,
                              hipStream_t stream) {
  (void)in_sizes; (void)n_in; (void)out_size; (void)ws_size;
  const void* x = d_in[0];
  const void* ei = d_in[1];
  const void* batch = d_in[2];
  const void *Wl[4], *bl[4], *Wr[4], *Wm[4], *bm[4];
  for (int l = 0; l < 4; l++) {
    Wl[l] = d_in[3 + l * 5 + 0];
    bl[l] = d_in[3 + l * 5 + 1];
    Wr[l] = d_in[3 + l * 5 + 2];
    Wm[l] = d_in[3 + l * 5 + 3];
    bm[l] = d_in[3 + l * 5 + 4];
  }
  const void* fc1W = d_in[23];
  const void* fc1b = d_in[24];
  const void* fc2W = d_in[25];
  const void* fc2b = d_in[26];

  char* ws = (char*)d_ws;
  size_t off = 0;
  auto alloc = [&](size_t bytes) -> void* {
    void* p = ws + off;
    off = (off + bytes + 255) & ~(size_t)255;
    return p;
  };
  int* flags   = (int*)alloc(16);
  int* row_ptr = (int*)alloc((NN + 1) * sizeof(int));
  int* cursor  = (int*)alloc(NN * sizeof(int));
  int* partial = (int*)alloc(NCHUNK * sizeof(int));
  int* col_src = (int*)alloc((size_t)EE * sizeof(int));
  int* src32   = (int*)alloc((size_t)EE * sizeof(int));
  int* dst32   = (int*)alloc((size_t)EE * sizeof(int));
  int* batch32 = (int*)alloc(NN * sizeof(int));
  int* gs      = (int*)alloc((GG + 1) * sizeof(int));
  u16* WcatT[4]; for (int l = 0; l < 4; l++) WcatT[l] = (u16*)alloc(256 * 512 * 2);
  u16* WmT[4];   for (int l = 0; l < 4; l++) WmT[l]   = (u16*)alloc(256 * 256 * 2);
  u16* bl_bf[4]; for (int l = 0; l < 4; l++) bl_bf[l] = (u16*)alloc(256 * 2);
  u16* bm_bf[4]; for (int l = 0; l < 4; l++) bm_bf[l] = (u16*)alloc(256 * 2);
  u16* fc1WT   = (u16*)alloc(256 * 1024 * 2);
  u16* fc1b_bf = (u16*)alloc(256 * 2);
  u16* fc2W_bf = (u16*)alloc(256 * 18 * 2);
  u16* fc2b_bf = (u16*)alloc(18 * 2);
  u16* xk      = (u16*)alloc((size_t)NN * DF * 2);
  u16* Acat    = (u16*)alloc((size_t)NN * 512 * 2);
  u16* tmp     = (u16*)alloc((size_t)NN * 256 * 2);
  u16* gpool   = (u16*)alloc(GG * 1024 * 2);
  float* fc1part = (float*)alloc(4 * GG * 256 * sizeof(float));

  hipMemsetAsync(flags, 0, 16, stream);
  hipMemsetAsync(cursor, 0, NN * sizeof(int), stream);
  detect_kernel<<<256, 256, 0, stream>>>((const u16*)x, (const unsigned*)ei, flags);

  ConvArgs CA; int blk = 0; int si = 0;
  auto addseg = [&](const void* s, u16* d, int n) {
    CA.s[si].src = s; CA.s[si].dst = d; CA.s[si].start_blk = blk; CA.s[si].n = n;
    blk += (n + 255) / 256; si++;
  };
  addseg(fc2W, fc2W_bf, 256 * 18);
  for (int l = 0; l < 4; l++) addseg(bl[l], bl_bf[l], 256);
  for (int l = 0; l < 4; l++) addseg(bm[l], bm_bf[l], 256);
  addseg(fc1b, fc1b_bf, 256);
  addseg(fc2b, fc2b_bf, 18);
  CA.nseg = si;
  conv_many<<<blk, 256, 0, stream>>>(CA, flags);
  conv_x_kernel<<<(NN * DF + 255) / 256, 256, 0, stream>>>(x, Acat + DF, xk, flags);
  conv_idx<<<(EE + 255) / 256, 256, 0, stream>>>(ei, batch, src32, dst32, batch32, cursor, flags);

  WPtrs P;
  for (int l = 0; l < 4; l++) {
    P.Wl[l] = Wl[l]; P.Wr[l] = Wr[l]; P.Wm[l] = Wm[l];
    P.WcatT[l] = WcatT[l]; P.WmT[l] = WmT[l];
  }
  P.fc1W = fc1W; P.fc1WT = fc1WT;
  prep_w_kernel<<<5120, 256, 0, stream>>>(P, flags);

  chunk_sum_kernel<<<NCHUNK, 256, 0, stream>>>(cursor, partial, NN);
  scan_partial_kernel<<<1, 256, 0, stream>>>(partial, NCHUNK, batch32, gs, NN);
  write_rowptr_kernel<<<NCHUNK, 256, 0, stream>>>(cursor, partial, row_ptr, NN);
  scatter_kernel<<<(EE + 255) / 256, 256, 0, stream>>>(src32, dst32, cursor, col_src, EE);

  int segblocks = (NN + 3) / 4;
  int gemmgrid = ((NN + 127) / 128) * 2;    // 782

  for (int l = 0; l < 4; l++) {
    if (l == 0) {
      segmax_kernel<16, true><<<segblocks, 256, 0, stream>>>(xk, DF, row_ptr, col_src,
                                                             Acat, 512, NN);
    } else {
      segmax_kernel<32, false><<<segblocks, 256, 0, stream>>>(Acat + 256, 512, row_ptr, col_src,
                                                              Acat, 512, NN);
    }
    int K = (l == 0) ? 256 : 512;
    gemm128<<<gemmgrid, 256, 0, stream>>>(Acat, 512, K, WcatT[l], bl_bf[l], tmp, 256, NN, 0);
    gemm128<<<gemmgrid, 256, 0, stream>>>(tmp, 256, 256, WmT[l], bm_bf[l], Acat + 256, 512, NN, 1);
    pool_kernel<<<GG, 1024, 0, stream>>>(Acat + 256, gs, gpool, l);
  }

  fc1_gemm<<<8, 256, 0, stream>>>(gpool, fc1WT, fc1part);
  fc2_head<<<GG, 256, 0, stream>>>(fc1part, fc1b_bf, fc2W_bf, fc2b_bf, d_out, flags);
}